// Round 1
// baseline (1017.729 us; speedup 1.0000x reference)
//
#include <hip/hip_runtime.h>
#include <math.h>

#define NFFT   2048
#define LOG2N  11
#define BB     8
#define WW     32
#define MM     16
#define NLAYER 4

__device__ __forceinline__ float gelu_f(float v) {
    return 0.5f * v * (1.0f + erff(v * 0.70710678118654752440f));
}

// Iterative radix-2 DIT. Expects bit-reversed input in s_re/s_im, produces
// natural-order output. twr/twi hold FORWARD twiddles:
//   twr[j]=cos(2*pi*j/N), twi[j]=-sin(2*pi*j/N)
__device__ inline void fft_stages(float* s_re, float* s_im,
                                  const float* twr, const float* twi,
                                  int t, bool inverse) {
    for (int s = 1; s <= LOG2N; ++s) {
        int half = 1 << (s - 1);
        __syncthreads();
        #pragma unroll
        for (int j = 0; j < 4; ++j) {
            int bid = t + j * 256;              // 0..1023 butterfly id
            int pos = bid & (half - 1);
            int grp = bid >> (s - 1);
            int i0  = (grp << s) + pos;
            int i1  = i0 + half;
            int ti  = pos << (LOG2N - s);
            float wr = twr[ti];
            float wi = inverse ? -twi[ti] : twi[ti];
            float ur = s_re[i0], ui = s_im[i0];
            float vr = s_re[i1], vi = s_im[i1];
            float tr = vr * wr - vi * wi;
            float tq = vr * wi + vi * wr;
            s_re[i0] = ur + tr; s_im[i0] = ui + tq;
            s_re[i1] = ur - tr; s_im[i1] = ui - tq;
        }
    }
    __syncthreads();
}

__device__ inline void fill_tw(float* twr, float* twi, int t) {
    for (int j = t; j < NFFT / 2; j += 256) {
        float a = (float)(6.283185307179586 / (double)NFFT) * (float)j;
        float sv, cv;
        sincosf(a, &sv, &cv);
        twr[j] = cv;
        twi[j] = -sv;
    }
}

// K0: h = gelu(fc0([x, grid])) for one (b,w) row, then forward FFT -> alpha
__global__ __launch_bounds__(256) void k_fc0_fft(
    const float* __restrict__ x, const float* __restrict__ fc0_w,
    const float* __restrict__ fc0_b, float2* __restrict__ alpha)
{
    __shared__ float s_re[NFFT], s_im[NFFT], s_twr[NFFT/2], s_twi[NFFT/2];
    int t = threadIdx.x;
    int row = blockIdx.x;            // b*32 + w
    int b = row >> 5, w = row & 31;
    fill_tw(s_twr, s_twi, t);
    float w0 = fc0_w[2*w], w1 = fc0_w[2*w+1], b0 = fc0_b[w];
    #pragma unroll
    for (int j = 0; j < 8; ++j) {
        int idx = t + j * 256;
        float xv = x[b * NFFT + idx];
        float gv = (float)idx * (1.0f / 2047.0f);     // linspace(0,1,L)
        float val = gelu_f(fmaf(w0, xv, fmaf(w1, gv, b0)));
        int r = __brev((unsigned)idx) >> (32 - LOG2N);
        s_re[r] = val; s_im[r] = 0.0f;
    }
    fft_stages(s_re, s_im, s_twr, s_twi, t, false);
    #pragma unroll
    for (int j = 0; j < 8; ++j) {
        int k = t + j * 256;
        alpha[row * NFFT + k] = make_float2(s_re[k], s_im[k]);
    }
}

// K2: fused per-frequency transfer function + channel einsum.
// hw_tot[i,o,k] = sum_m res/(lam_k - pole) + conv_w[o,i] + spec-fold(k)
// Y[b,o,k] = sum_i alpha[b,i,k]*hw_tot[i,o,k]  (+ L*conv_b[o] at k==0)
__global__ __launch_bounds__(1024) void k_apply(
    const float2* __restrict__ alpha, float2* __restrict__ Y,
    const float* __restrict__ pole_re, const float* __restrict__ pole_im,
    const float* __restrict__ res_re,  const float* __restrict__ res_im,
    const float* __restrict__ spec_re, const float* __restrict__ spec_im,
    const float* __restrict__ conv_w,  const float* __restrict__ conv_b,
    const float* __restrict__ tgrid, int layer)
{
    __shared__ float2 s_hw[4][32][33];   // [kk][o][i], padded to kill conflicts
    int t = threadIdx.x;
    int i = t & 31, o = t >> 5;          // phase-1 roles (1024 = 32x32)
    int k0 = blockIdx.x * 8;             // 8 frequencies per block
    float dt = tgrid[1] - tgrid[0];
    float fscale = 6.2831853071795864769f / ((float)NFFT * dt);
    int pb = ((layer * WW + i) * WW + o) * MM;
    float pre[16], pim[16], rre[16], rim[16];
    #pragma unroll
    for (int q = 0; q < 4; ++q) {
        *(float4*)&pre[4*q] = *(const float4*)&pole_re[pb + 4*q];
        *(float4*)&pim[4*q] = *(const float4*)&pole_im[pb + 4*q];
        *(float4*)&rre[4*q] = *(const float4*)&res_re [pb + 4*q];
        *(float4*)&rim[4*q] = *(const float4*)&res_im [pb + 4*q];
    }
    float cw = conv_w[layer * WW * WW + o * WW + i];
    int o2 = t & 31, b2 = (t >> 5) & 7, kk2 = t >> 8;   // phase-2 roles

    for (int iter = 0; iter < 2; ++iter) {
        #pragma unroll
        for (int kk = 0; kk < 4; ++kk) {
            int k = k0 + iter * 4 + kk;
            int ks = (k < NFFT / 2) ? k : k - NFFT;     // fftfreq sign
            float f = fscale * (float)ks;
            float hr = cw, hi = 0.0f;
            #pragma unroll
            for (int m = 0; m < 16; ++m) {
                float c = -pre[m];
                float d = f - pim[m];
                float inv = __builtin_amdgcn_rcpf(fmaf(c, c, d * d));
                hr = fmaf(fmaf(rre[m], c,  rim[m] * d), inv, hr);
                hi = fmaf(fmaf(rim[m], c, -rre[m] * d), inv, hi);
            }
            if (k < MM) {                       // spectral branch, direct bins
                hr += spec_re[pb + k];
                hi += spec_im[pb + k];
            } else if (k > NFFT - MM) {         // conj bins (alpha Hermitian)
                int si = pb + (NFFT - k);
                hr += spec_re[si];
                hi -= spec_im[si];
            }
            s_hw[kk][o][i] = make_float2(hr, hi);
        }
        __syncthreads();
        {
            int k = k0 + iter * 4 + kk2;
            float yr = 0.0f, yi = 0.0f;
            const float2* arow = alpha + b2 * WW * NFFT + k;
            #pragma unroll
            for (int ii = 0; ii < 32; ++ii) {
                float2 a  = arow[ii * NFFT];    // broadcast across lanes
                float2 hh = s_hw[kk2][o2][ii];
                yr += a.x * hh.x - a.y * hh.y;
                yi += a.x * hh.y + a.y * hh.x;
            }
            if (k == 0) yr += (float)NFFT * conv_b[layer * WW + o2];
            Y[(b2 * WW + o2) * NFFT + k] = make_float2(yr, yi);
        }
        __syncthreads();
    }
}

// K4: inverse FFT of Y, take Re/N, gelu -> h ; if !LAST, forward-FFT h
// in-place to produce next layer's alpha (h never touches HBM mid-network).
template<bool LAST>
__global__ __launch_bounds__(256) void k_ifft_gelu_fft(
    const float2* __restrict__ Y, float2* __restrict__ alpha,
    float* __restrict__ hout)
{
    __shared__ float s_re[NFFT], s_im[NFFT], s_twr[NFFT/2], s_twi[NFFT/2];
    int t = threadIdx.x;
    int row = blockIdx.x;
    fill_tw(s_twr, s_twi, t);
    #pragma unroll
    for (int j = 0; j < 8; ++j) {
        int k = t + j * 256;
        float2 v = Y[row * NFFT + k];
        int r = __brev((unsigned)k) >> (32 - LOG2N);
        s_re[r] = v.x; s_im[r] = v.y;
    }
    fft_stages(s_re, s_im, s_twr, s_twi, t, true);    // unnormalized inverse
    float vals[8];
    #pragma unroll
    for (int j = 0; j < 8; ++j) {
        int l = t + j * 256;
        vals[j] = gelu_f(s_re[l] * (1.0f / (float)NFFT));
    }
    if (LAST) {
        #pragma unroll
        for (int j = 0; j < 8; ++j) hout[row * NFFT + t + j * 256] = vals[j];
    } else {
        __syncthreads();                  // everyone done reading s_re
        #pragma unroll
        for (int j = 0; j < 8; ++j) {
            int idx = t + j * 256;
            int r = __brev((unsigned)idx) >> (32 - LOG2N);
            s_re[r] = vals[j]; s_im[r] = 0.0f;
        }
        fft_stages(s_re, s_im, s_twr, s_twi, t, false);
        #pragma unroll
        for (int j = 0; j < 8; ++j) {
            int k = t + j * 256;
            alpha[row * NFFT + k] = make_float2(s_re[k], s_im[k]);
        }
    }
}

// K5: out[b,l] = fc2_b + sum_n fc2_w[n]*gelu(fc1_b[n] + sum_w fc1_w[n,w]*h[b,w,l])
__global__ __launch_bounds__(256) void k_head(
    const float* __restrict__ h, const float* __restrict__ fc1_w,
    const float* __restrict__ fc1_b, const float* __restrict__ fc2_w,
    const float* __restrict__ fc2_b, float* __restrict__ out)
{
    __shared__ float s_w1[128 * 32];
    __shared__ float s_b1[128];
    __shared__ float s_w2[128];
    int t = threadIdx.x;
    for (int j = t; j < 128 * 32; j += 256) s_w1[j] = fc1_w[j];
    if (t < 128) { s_b1[t] = fc1_b[t]; s_w2[t] = fc2_w[t]; }
    __syncthreads();
    int gid = blockIdx.x * 256 + t;        // b*2048 + l
    int b = gid >> LOG2N;
    int l = gid & (NFFT - 1);
    float hreg[32];
    #pragma unroll
    for (int w = 0; w < 32; ++w) hreg[w] = h[(b * WW + w) * NFFT + l];
    float acc = fc2_b[0];
    for (int n = 0; n < 128; ++n) {
        float a = s_b1[n];
        #pragma unroll
        for (int w = 0; w < 32; ++w) a = fmaf(s_w1[n * 32 + w], hreg[w], a);
        acc = fmaf(s_w2[n], gelu_f(a), acc);
    }
    out[gid] = acc;
}

extern "C" void kernel_launch(void* const* d_in, const int* in_sizes, int n_in,
                              void* d_out, int out_size, void* d_ws, size_t ws_size,
                              hipStream_t stream)
{
    const float* x       = (const float*)d_in[0];
    const float* tg      = (const float*)d_in[1];
    const float* fc0_w   = (const float*)d_in[2];
    const float* fc0_b   = (const float*)d_in[3];
    const float* pole_re = (const float*)d_in[4];
    const float* pole_im = (const float*)d_in[5];
    const float* res_re  = (const float*)d_in[6];
    const float* res_im  = (const float*)d_in[7];
    const float* spec_re = (const float*)d_in[8];
    const float* spec_im = (const float*)d_in[9];
    const float* conv_w  = (const float*)d_in[10];
    const float* conv_b  = (const float*)d_in[11];
    const float* fc1_w   = (const float*)d_in[12];
    const float* fc1_b   = (const float*)d_in[13];
    const float* fc2_w   = (const float*)d_in[14];
    const float* fc2_b   = (const float*)d_in[15];
    float* out = (float*)d_out;

    char* ws = (char*)d_ws;
    const size_t plane = (size_t)(BB * WW) * NFFT * sizeof(float2);  // 4 MiB
    float2* alpha = (float2*)ws;
    float2* Yb    = (float2*)(ws + plane);
    float*  hbuf  = (float*)(ws + 2 * plane);

    hipLaunchKernelGGL(k_fc0_fft, dim3(BB * WW), dim3(256), 0, stream,
                       x, fc0_w, fc0_b, alpha);
    for (int layer = 0; layer < NLAYER; ++layer) {
        hipLaunchKernelGGL(k_apply, dim3(NFFT / 8), dim3(1024), 0, stream,
                           alpha, Yb, pole_re, pole_im, res_re, res_im,
                           spec_re, spec_im, conv_w, conv_b, tg, layer);
        if (layer < NLAYER - 1)
            hipLaunchKernelGGL((k_ifft_gelu_fft<false>), dim3(BB * WW), dim3(256),
                               0, stream, Yb, alpha, (float*)nullptr);
        else
            hipLaunchKernelGGL((k_ifft_gelu_fft<true>), dim3(BB * WW), dim3(256),
                               0, stream, Yb, alpha, hbuf);
    }
    hipLaunchKernelGGL(k_head, dim3(BB * NFFT / 256), dim3(256), 0, stream,
                       hbuf, fc1_w, fc1_b, fc2_w, fc2_b, out);
}

// Round 2
// 257.539 us; speedup vs baseline: 3.9518x; 3.9518x over previous
//
#include <hip/hip_runtime.h>
#include <math.h>

#define NFFT   2048
#define LOG2N  11
#define BB     8
#define WW     32
#define MM     16
#define NLAYER 4

__device__ __forceinline__ float gelu_f(float v) {
    return 0.5f * v * (1.0f + erff(v * 0.70710678118654752440f));
}

// Iterative radix-2 DIT. Expects bit-reversed input in s_re/s_im, produces
// natural-order output. twr/twi hold FORWARD twiddles:
//   twr[j]=cos(2*pi*j/N), twi[j]=-sin(2*pi*j/N)
__device__ inline void fft_stages(float* s_re, float* s_im,
                                  const float* twr, const float* twi,
                                  int t, bool inverse) {
    for (int s = 1; s <= LOG2N; ++s) {
        int half = 1 << (s - 1);
        __syncthreads();
        #pragma unroll
        for (int j = 0; j < 4; ++j) {
            int bid = t + j * 256;              // 0..1023 butterfly id
            int pos = bid & (half - 1);
            int grp = bid >> (s - 1);
            int i0  = (grp << s) + pos;
            int i1  = i0 + half;
            int ti  = pos << (LOG2N - s);
            float wr = twr[ti];
            float wi = inverse ? -twi[ti] : twi[ti];
            float ur = s_re[i0], ui = s_im[i0];
            float vr = s_re[i1], vi = s_im[i1];
            float tr = vr * wr - vi * wi;
            float tq = vr * wi + vi * wr;
            s_re[i0] = ur + tr; s_im[i0] = ui + tq;
            s_re[i1] = ur - tr; s_im[i1] = ui - tq;
        }
    }
    __syncthreads();
}

__device__ inline void fill_tw(float* twr, float* twi, int t) {
    for (int j = t; j < NFFT / 2; j += 256) {
        float a = (float)(6.283185307179586 / (double)NFFT) * (float)j;
        float sv, cv;
        __sincosf(a, &sv, &cv);
        twr[j] = cv;
        twi[j] = -sv;
    }
}

// K0: h = gelu(fc0([x, grid])) for one (b,w) row, then forward FFT -> alpha
__global__ __launch_bounds__(256) void k_fc0_fft(
    const float* __restrict__ x, const float* __restrict__ fc0_w,
    const float* __restrict__ fc0_b, float2* __restrict__ alpha)
{
    __shared__ float s_re[NFFT], s_im[NFFT], s_twr[NFFT/2], s_twi[NFFT/2];
    int t = threadIdx.x;
    int row = blockIdx.x;            // b*32 + w
    int b = row >> 5, w = row & 31;
    fill_tw(s_twr, s_twi, t);
    float w0 = fc0_w[2*w], w1 = fc0_w[2*w+1], b0 = fc0_b[w];
    #pragma unroll
    for (int j = 0; j < 8; ++j) {
        int idx = t + j * 256;
        float xv = x[b * NFFT + idx];
        float gv = (float)idx * (1.0f / 2047.0f);     // linspace(0,1,L)
        float val = gelu_f(fmaf(w0, xv, fmaf(w1, gv, b0)));
        int r = __brev((unsigned)idx) >> (32 - LOG2N);
        s_re[r] = val; s_im[r] = 0.0f;
    }
    fft_stages(s_re, s_im, s_twr, s_twi, t, false);
    #pragma unroll
    for (int j = 0; j < 8; ++j) {
        int k = t + j * 256;
        alpha[row * NFFT + k] = make_float2(s_re[k], s_im[k]);
    }
}

// K2: fused per-frequency transfer function + channel einsum.
// H[i,o,k] = sum_m res/(lam_k - pole) + conv_w[o,i] + spec-fold(k)
// Y[b,o,k] = sum_i alpha[b,i,k]*H[i,o,k]  (+ L*conv_b[o] at k==0)
// 256 threads, 8 k's per block. Phase 1: thread walks 4 (i,o) pairs with
// modes OUTER, k INNER (acc[8] complex in regs; params transient -> no spill).
__global__ __launch_bounds__(256) void k_apply(
    const float2* __restrict__ alpha, float2* __restrict__ Y,
    const float* __restrict__ pole_re, const float* __restrict__ pole_im,
    const float* __restrict__ res_re,  const float* __restrict__ res_im,
    const float* __restrict__ spec_re, const float* __restrict__ spec_im,
    const float* __restrict__ conv_w,  const float* __restrict__ conv_b,
    const float* __restrict__ tgrid, int layer)
{
    __shared__ float2 s_hw[WW][8][33];   // [o][kk][i], i padded 32->33
    int t = threadIdx.x;
    int k0 = blockIdx.x * 8;
    float dt = tgrid[1] - tgrid[0];
    float fscale = 6.2831853071795864769f / ((float)NFFT * dt);
    float fk[8];
    #pragma unroll
    for (int kk = 0; kk < 8; ++kk) {
        int k = k0 + kk;
        int ks = (k < NFFT / 2) ? k : k - NFFT;     // fftfreq sign
        fk[kk] = fscale * (float)ks;
    }

    for (int pq = 0; pq < 4; ++pq) {             // 4 (i,o) pairs per thread
        int q = t + pq * 256;
        int i = q & 31, o = q >> 5;
        int pb = ((layer * WW + i) * WW + o) * MM;
        float cw = conv_w[(layer * WW + o) * WW + i];
        float2 acc[8];
        #pragma unroll
        for (int kk = 0; kk < 8; ++kk) acc[kk] = make_float2(cw, 0.0f);
        #pragma unroll
        for (int mq = 0; mq < 4; ++mq) {
            float4 P_re = *(const float4*)&pole_re[pb + 4 * mq];
            float4 P_im = *(const float4*)&pole_im[pb + 4 * mq];
            float4 R_re = *(const float4*)&res_re [pb + 4 * mq];
            float4 R_im = *(const float4*)&res_im [pb + 4 * mq];
            #pragma unroll
            for (int mm = 0; mm < 4; ++mm) {
                float pr = (&P_re.x)[mm], pi = (&P_im.x)[mm];
                float rr = (&R_re.x)[mm], ri = (&R_im.x)[mm];
                float c  = -pr;
                float c2 = c * c;
                float rc = rr * c;          // re(res)*c
                float ic = ri * c;          // im(res)*c
                #pragma unroll
                for (int kk = 0; kk < 8; ++kk) {
                    float d   = fk[kk] - pi;
                    float inv = __builtin_amdgcn_rcpf(fmaf(d, d, c2));
                    acc[kk].x = fmaf(fmaf(ri, d, rc), inv, acc[kk].x);
                    acc[kk].y = fmaf(fmaf(-rr, d, ic), inv, acc[kk].y);
                }
            }
        }
        if (k0 < MM || k0 >= NFFT - MM) {        // spectral-conv fold (rare blocks)
            #pragma unroll
            for (int kk = 0; kk < 8; ++kk) {
                int k = k0 + kk;
                if (k < MM) {
                    acc[kk].x += spec_re[pb + k];
                    acc[kk].y += spec_im[pb + k];
                } else if (k > NFFT - MM) {      // conj bins (alpha Hermitian)
                    acc[kk].x += spec_re[pb + NFFT - k];
                    acc[kk].y -= spec_im[pb + NFFT - k];
                }
            }
        }
        #pragma unroll
        for (int kk = 0; kk < 8; ++kk) s_hw[o][kk][i] = acc[kk];
    }
    __syncthreads();

    // Phase 2: lane = (o2, kl). 8 consecutive k per 8 lanes -> alpha loads
    // hit one cacheline per instr; Y writes 64B-contiguous.
    int kl = t & 7, o2 = t >> 3;
    int k = k0 + kl;
    float2 acc2[8];
    #pragma unroll
    for (int b = 0; b < 8; ++b) acc2[b] = make_float2(0.0f, 0.0f);
    const float2* ab = alpha + k;
    #pragma unroll 4
    for (int ii = 0; ii < 32; ++ii) {
        float2 hh = s_hw[o2][kl][ii];
        #pragma unroll
        for (int b = 0; b < 8; ++b) {
            float2 a = ab[(b * WW + ii) * NFFT];
            acc2[b].x = fmaf(a.x, hh.x, fmaf(-a.y, hh.y, acc2[b].x));
            acc2[b].y = fmaf(a.x, hh.y, fmaf( a.y, hh.x, acc2[b].y));
        }
    }
    if (k == 0) {
        float cb = (float)NFFT * conv_b[layer * WW + o2];
        #pragma unroll
        for (int b = 0; b < 8; ++b) acc2[b].x += cb;
    }
    #pragma unroll
    for (int b = 0; b < 8; ++b) Y[(b * WW + o2) * NFFT + k] = acc2[b];
}

// K4: inverse FFT of Y, take Re/N, gelu -> h ; if !LAST, forward-FFT h
// in-place to produce next layer's alpha (h never touches HBM mid-network).
template<bool LAST>
__global__ __launch_bounds__(256) void k_ifft_gelu_fft(
    const float2* __restrict__ Y, float2* __restrict__ alpha,
    float* __restrict__ hout)
{
    __shared__ float s_re[NFFT], s_im[NFFT], s_twr[NFFT/2], s_twi[NFFT/2];
    int t = threadIdx.x;
    int row = blockIdx.x;
    fill_tw(s_twr, s_twi, t);
    #pragma unroll
    for (int j = 0; j < 8; ++j) {
        int k = t + j * 256;
        float2 v = Y[row * NFFT + k];
        int r = __brev((unsigned)k) >> (32 - LOG2N);
        s_re[r] = v.x; s_im[r] = v.y;
    }
    fft_stages(s_re, s_im, s_twr, s_twi, t, true);    // unnormalized inverse
    float vals[8];
    #pragma unroll
    for (int j = 0; j < 8; ++j) {
        int l = t + j * 256;
        vals[j] = gelu_f(s_re[l] * (1.0f / (float)NFFT));
    }
    if (LAST) {
        #pragma unroll
        for (int j = 0; j < 8; ++j) hout[row * NFFT + t + j * 256] = vals[j];
    } else {
        __syncthreads();                  // everyone done reading s_re
        #pragma unroll
        for (int j = 0; j < 8; ++j) {
            int idx = t + j * 256;
            int r = __brev((unsigned)idx) >> (32 - LOG2N);
            s_re[r] = vals[j]; s_im[r] = 0.0f;
        }
        fft_stages(s_re, s_im, s_twr, s_twi, t, false);
        #pragma unroll
        for (int j = 0; j < 8; ++j) {
            int k = t + j * 256;
            alpha[row * NFFT + k] = make_float2(s_re[k], s_im[k]);
        }
    }
}

// K5: out[b,l] = fc2_b + sum_n fc2_w[n]*gelu(fc1_b[n] + sum_w fc1_w[n,w]*h[b,w,l])
__global__ __launch_bounds__(256) void k_head(
    const float* __restrict__ h, const float* __restrict__ fc1_w,
    const float* __restrict__ fc1_b, const float* __restrict__ fc2_w,
    const float* __restrict__ fc2_b, float* __restrict__ out)
{
    __shared__ float s_w1[128 * 32];
    __shared__ float s_b1[128];
    __shared__ float s_w2[128];
    int t = threadIdx.x;
    for (int j = t; j < 128 * 32; j += 256) s_w1[j] = fc1_w[j];
    if (t < 128) { s_b1[t] = fc1_b[t]; s_w2[t] = fc2_w[t]; }
    __syncthreads();
    int gid = blockIdx.x * 256 + t;        // b*2048 + l
    int b = gid >> LOG2N;
    int l = gid & (NFFT - 1);
    float hreg[32];
    #pragma unroll
    for (int w = 0; w < 32; ++w) hreg[w] = h[(b * WW + w) * NFFT + l];
    float acc = fc2_b[0];
    for (int n = 0; n < 128; ++n) {
        float a = s_b1[n];
        #pragma unroll
        for (int w = 0; w < 32; ++w) a = fmaf(s_w1[n * 32 + w], hreg[w], a);
        acc = fmaf(s_w2[n], gelu_f(a), acc);
    }
    out[gid] = acc;
}

extern "C" void kernel_launch(void* const* d_in, const int* in_sizes, int n_in,
                              void* d_out, int out_size, void* d_ws, size_t ws_size,
                              hipStream_t stream)
{
    const float* x       = (const float*)d_in[0];
    const float* tg      = (const float*)d_in[1];
    const float* fc0_w   = (const float*)d_in[2];
    const float* fc0_b   = (const float*)d_in[3];
    const float* pole_re = (const float*)d_in[4];
    const float* pole_im = (const float*)d_in[5];
    const float* res_re  = (const float*)d_in[6];
    const float* res_im  = (const float*)d_in[7];
    const float* spec_re = (const float*)d_in[8];
    const float* spec_im = (const float*)d_in[9];
    const float* conv_w  = (const float*)d_in[10];
    const float* conv_b  = (const float*)d_in[11];
    const float* fc1_w   = (const float*)d_in[12];
    const float* fc1_b   = (const float*)d_in[13];
    const float* fc2_w   = (const float*)d_in[14];
    const float* fc2_b   = (const float*)d_in[15];
    float* out = (float*)d_out;

    char* ws = (char*)d_ws;
    const size_t plane = (size_t)(BB * WW) * NFFT * sizeof(float2);  // 4 MiB
    float2* alpha = (float2*)ws;
    float2* Yb    = (float2*)(ws + plane);
    float*  hbuf  = (float*)(ws + 2 * plane);

    hipLaunchKernelGGL(k_fc0_fft, dim3(BB * WW), dim3(256), 0, stream,
                       x, fc0_w, fc0_b, alpha);
    for (int layer = 0; layer < NLAYER; ++layer) {
        hipLaunchKernelGGL(k_apply, dim3(NFFT / 8), dim3(256), 0, stream,
                           alpha, Yb, pole_re, pole_im, res_re, res_im,
                           spec_re, spec_im, conv_w, conv_b, tg, layer);
        if (layer < NLAYER - 1)
            hipLaunchKernelGGL((k_ifft_gelu_fft<false>), dim3(BB * WW), dim3(256),
                               0, stream, Yb, alpha, (float*)nullptr);
        else
            hipLaunchKernelGGL((k_ifft_gelu_fft<true>), dim3(BB * WW), dim3(256),
                               0, stream, Yb, alpha, hbuf);
    }
    hipLaunchKernelGGL(k_head, dim3(BB * NFFT / 256), dim3(256), 0, stream,
                       hbuf, fc1_w, fc1_b, fc2_w, fc2_b, out);
}